// Round 1
// baseline (489.382 us; speedup 1.0000x reference)
//
#include <hip/hip_runtime.h>
#include <cstdint>

// Static problem sizes
#define BB 32
#define CC 512
#define NSQ 4096      // N*N
#define SS 128
#define MM 256
#define PP 2080
#define JJ (BB*PP)    // 66560

// ws layout (byte offsets), total ~906 KB
#define WS_SN     0         // sents_norm: 128*512 f32 = 262144 B
#define WS_IDX    262144    // idx: 2080 i32 = 8320 B
#define WS_TOPIDX 270464    // top_idx: 256 i32 = 1024 B
#define WS_TV     271488    // topk_v: 256*512 f32 = 524288 B
#define WS_IV     795776    // iv_all: 256*128 f32 = 131072 B
#define WS_NEGQ   926848    // neg_sum_q: 128 f32 = 512 B

// ---------------------------------------------------------------------------
// prep: blocks 0..127 normalize sents rows; 128..143 build idx table;
//       144 zeroes neg_sum_q.
__global__ void k_prep(const float* __restrict__ sents, float* __restrict__ sn,
                       int* __restrict__ idx, float* __restrict__ negq) {
    const int blk = blockIdx.x, t = threadIdx.x;
    if (blk < 128) {
        __shared__ float red[256];
        const float* row = sents + (size_t)blk * CC;
        float x0 = row[t], x1 = row[t + 256];
        red[t] = x0 * x0 + x1 * x1;
        __syncthreads();
        for (int off = 128; off > 0; off >>= 1) {
            if (t < off) red[t] += red[t + off];
            __syncthreads();
        }
        float rn = 1.0f / fmaxf(sqrtf(red[0]), 1e-12f);
        sn[(size_t)blk * CC + t]       = x0 * rn;
        sn[(size_t)blk * CC + t + 256] = x1 * rn;
    } else if (blk < 144) {
        int i = (blk - 128) * 256 + t;      // 0..4095
        int r = i >> 6, c = i & 63;
        if (c >= r) {
            int p = r * 64 - (r * (r - 1)) / 2 + (c - r);
            idx[p] = i;
        }
    } else {
        if (t < 128) negq[t] = 0.0f;
    }
}

// ---------------------------------------------------------------------------
// argmax of iou2ds over the P valid proposals, per target m (tie -> lowest p)
__global__ void k_argmax(const float* __restrict__ iou2ds, const int* __restrict__ idx,
                         int* __restrict__ topidx) {
    const int m = blockIdx.x, t = threadIdx.x;
    __shared__ float sv[256];
    __shared__ int   si[256];
    float best = -1e30f; int bi = PP;
    const float* row = iou2ds + (size_t)m * NSQ;
    for (int p = t; p < PP; p += 256) {
        float v = row[idx[p]];
        if (v > best || (v == best && p < bi)) { best = v; bi = p; }
    }
    sv[t] = best; si[t] = bi;
    __syncthreads();
    for (int off = 128; off > 0; off >>= 1) {
        if (t < off) {
            float v2 = sv[t + off]; int i2 = si[t + off];
            if (v2 > sv[t] || (v2 == sv[t] && i2 < si[t])) { sv[t] = v2; si[t] = i2; }
        }
        __syncthreads();
    }
    if (t == 0) topidx[m] = si[0];
}

// ---------------------------------------------------------------------------
// gather the top-1 column per target and l2-normalize it -> tv[m][512]
__global__ void k_topkv(const float* __restrict__ video, const int* __restrict__ idx,
                        const int* __restrict__ topidx, float* __restrict__ tv) {
    const int m = blockIdx.x, t = threadIdx.x;
    __shared__ float red[256];
    const int b = m >> 3;                    // scatter_m2v
    const int flat = idx[topidx[m]];
    const float* base = video + (size_t)b * CC * NSQ + flat;
    float x0 = base[(size_t)t * NSQ];
    float x1 = base[(size_t)(t + 256) * NSQ];
    red[t] = x0 * x0 + x1 * x1;
    __syncthreads();
    for (int off = 128; off > 0; off >>= 1) {
        if (t < off) red[t] += red[t + off];
        __syncthreads();
    }
    float rn = 1.0f / fmaxf(sqrtf(red[0]), 1e-12f);
    tv[(size_t)m * CC + t]       = x0 * rn;
    tv[(size_t)m * CC + t + 256] = x1 * rn;
}

// ---------------------------------------------------------------------------
// iv_all[m][s] = dot(tv[m], sn[s])   (256 x 128 x 512 mini-GEMM)
__global__ void k_ivall(const float* __restrict__ tv, const float* __restrict__ sn,
                        float* __restrict__ iv) {
    const int m = blockIdx.x, t = threadIdx.x;   // 128 threads
    __shared__ float4 tvs[128];
    const float4* tv4 = (const float4*)(tv + (size_t)m * CC);
    tvs[t] = tv4[t];
    __syncthreads();
    const float4* sn4 = (const float4*)(sn + (size_t)t * CC);
    float acc = 0.f;
#pragma unroll 4
    for (int c = 0; c < 128; c++) {
        float4 a = tvs[c]; float4 b = sn4[c];
        acc += a.x * b.x + a.y * b.y + a.z * b.z + a.w * b.w;
    }
    iv[(size_t)m * SS + t] = acc;
}

// ---------------------------------------------------------------------------
// Big fused kernel: for 128-column tile of the (S=128) x (J=66560) score
// matrix: GEMM vs raw video columns with fused sum-of-squares, then
// rnorm scale, masked exp, per-row reduce, atomicAdd into negq[s].
__global__ __launch_bounds__(256)
void k_big(const float* __restrict__ video, const float* __restrict__ sn,
           const float* __restrict__ iou2d, const int* __restrict__ idx,
           float* __restrict__ negq) {
    __shared__ float sA[16][132];      // sents chunk, transposed, padded
    __shared__ float vB[16][128];      // raw video chunk
    __shared__ float colrn[128];
    __shared__ int   colb[128], colflat[128];
    __shared__ float sq2[2][128];
    __shared__ float red[128][16];

    const int t  = threadIdx.x;
    const int tx = t & 15, ty = t >> 4;
    const int j0 = blockIdx.x * 128;

    // per-column metadata (epilogue use)
    if (t < 128) {
        int col = j0 + t;
        int b = col / PP;
        int p = col - b * PP;
        colb[t] = b;
        colflat[t] = idx[p];
    }

    // loader config: thread t loads column jj, k-halves kh*8..kh*8+7
    const int jj = t & 127;
    const int kh = t >> 7;   // 0 or 1
    {
        // nothing else; metadata for loader below
    }
    int colL = j0 + jj;
    int bL = colL / PP;
    int pL = colL - bL * PP;
    int flatL = idx[pL];
    const float* vptr = video + (size_t)bL * (CC * NSQ) + flatL + (size_t)kh * 8 * NSQ;

    float acc[8][8];
#pragma unroll
    for (int i = 0; i < 8; i++)
#pragma unroll
        for (int j = 0; j < 8; j++) acc[i][j] = 0.f;

    float sqa = 0.f;

    for (int k0 = 0; k0 < CC; k0 += 16) {
        __syncthreads();
        // stage sents chunk (transposed into sA[kk][s])
        {
            int lin = t;
#pragma unroll
            for (int it = 0; it < 2; it++) {
                int s = lin >> 2, q = lin & 3;
                float4 w = *(const float4*)(sn + (size_t)s * CC + k0 + q * 4);
                sA[q * 4 + 0][s] = w.x;
                sA[q * 4 + 1][s] = w.y;
                sA[q * 4 + 2][s] = w.z;
                sA[q * 4 + 3][s] = w.w;
                lin += 256;
            }
        }
        // stage video chunk (gathered columns) + fused sum of squares
        {
            const float* vp = vptr + (size_t)k0 * NSQ;
#pragma unroll
            for (int i = 0; i < 8; i++) {
                float x = vp[(size_t)i * NSQ];
                sqa += x * x;
                vB[kh * 8 + i][jj] = x;
            }
        }
        __syncthreads();
#pragma unroll
        for (int kk = 0; kk < 16; kk++) {
            float4 a0 = *(const float4*)&sA[kk][ty * 8];
            float4 a1 = *(const float4*)&sA[kk][ty * 8 + 4];
            float4 b0 = *(const float4*)&vB[kk][tx * 8];
            float4 b1 = *(const float4*)&vB[kk][tx * 8 + 4];
            float av[8] = {a0.x, a0.y, a0.z, a0.w, a1.x, a1.y, a1.z, a1.w};
            float bv[8] = {b0.x, b0.y, b0.z, b0.w, b1.x, b1.y, b1.z, b1.w};
#pragma unroll
            for (int i = 0; i < 8; i++)
#pragma unroll
                for (int j = 0; j < 8; j++)
                    acc[i][j] += av[i] * bv[j];
        }
    }

    // column reciprocal norms
    sq2[kh][jj] = sqa;
    __syncthreads();
    if (t < 128) {
        float s2 = sq2[0][t] + sq2[1][t];
        colrn[t] = 1.0f / fmaxf(sqrtf(s2), 1e-12f);
    }
    __syncthreads();

    // epilogue: scale, exp, mask, per-row partial sums
    float rowsum[8];
#pragma unroll
    for (int i = 0; i < 8; i++) rowsum[i] = 0.f;

#pragma unroll
    for (int j = 0; j < 8; j++) {
        int cidx = tx * 8 + j;
        float rn = colrn[cidx];
        int b = colb[cidx];
        int flat = colflat[cidx];
#pragma unroll
        for (int i = 0; i < 8; i++) {
            int s = ty * 8 + i;
            float sc = acc[i][j] * rn;
            float e = expf(sc * 10.0f);                 // / T_TEMP
            if ((s >> 2) == b) {                        // same video block
                if (iou2d[(size_t)s * NSQ + flat] > 0.5f) e = 0.f;  // positive -> excluded
            }
            rowsum[i] += e;
        }
    }
#pragma unroll
    for (int i = 0; i < 8; i++) red[ty * 8 + i][tx] = rowsum[i];
    __syncthreads();
    if (t < 128) {
        float tot = 0.f;
#pragma unroll
        for (int x = 0; x < 16; x++) tot += red[t][x];
        atomicAdd(&negq[t], tot);
    }
}

// ---------------------------------------------------------------------------
// final losses
__global__ void k_final(const float* __restrict__ iv, const float* __restrict__ negq,
                        float* __restrict__ out) {
    const int t = threadIdx.x;   // 256 = M
    __shared__ float rv[256], rq[256];
    const float* row = iv + (size_t)t * SS;
    const int ms = t >> 1;       // scatter_m2s
    float pos = row[ms];
    float nv = 0.f;
    for (int s = 0; s < SS; s++) {
        float e = expf(row[s] * 10.0f);
        if (s == ms) e = 0.f;
        nv += e;
    }
    float pe = expf(pos * 10.0f);
    float lv = logf(pe + nv) - pos * 10.0f;
    float lq = logf(pe + negq[ms]) - pos * 10.0f;
    rv[t] = lv; rq[t] = lq;
    __syncthreads();
    for (int off = 128; off > 0; off >>= 1) {
        if (t < off) { rv[t] += rv[t + off]; rq[t] += rq[t + off]; }
        __syncthreads();
    }
    if (t == 0) {
        float liv = rv[0] / 256.f, liq = rq[0] / 256.f;
        out[0] = liv + liq;   // total (WEIGHT=1)
        out[1] = liv;
        out[2] = liq;
    }
}

// ---------------------------------------------------------------------------
extern "C" void kernel_launch(void* const* d_in, const int* in_sizes, int n_in,
                              void* d_out, int out_size, void* d_ws, size_t ws_size,
                              hipStream_t stream) {
    const float* video  = (const float*)d_in[0];   // (B,C,N,N)
    const float* sents  = (const float*)d_in[1];   // (S,C)
    // d_in[2]=num_sentences (always 4), d_in[3]=num_targets (always 2) — static
    const float* iou2d  = (const float*)d_in[4];   // (S,N,N)
    const float* iou2ds = (const float*)d_in[5];   // (M,N,N)
    // d_in[6]=mask2d (static triu), d_in[7]=epoch (unused: DNS branch off)
    float* out = (float*)d_out;

    char* ws = (char*)d_ws;
    float* sn     = (float*)(ws + WS_SN);
    int*   idx    = (int*)  (ws + WS_IDX);
    int*   topidx = (int*)  (ws + WS_TOPIDX);
    float* tv     = (float*)(ws + WS_TV);
    float* iv     = (float*)(ws + WS_IV);
    float* negq   = (float*)(ws + WS_NEGQ);

    k_prep  <<<145, 256, 0, stream>>>(sents, sn, idx, negq);
    k_argmax<<<MM,  256, 0, stream>>>(iou2ds, idx, topidx);
    k_topkv <<<MM,  256, 0, stream>>>(video, idx, topidx, tv);
    k_ivall <<<MM,  128, 0, stream>>>(tv, sn, iv);
    k_big   <<<JJ / 128, 256, 0, stream>>>(video, sn, iou2d, idx, negq);
    k_final <<<1,   256, 0, stream>>>(iv, negq, out);
}

// Round 2
// 438.979 us; speedup vs baseline: 1.1148x; 1.1148x over previous
//
#include <hip/hip_runtime.h>
#include <cstdint>

// Static problem sizes
#define BB 32
#define CC 512
#define NSQ 4096      // N*N
#define SS 128
#define MM 256
#define PP 2080
#define JJ (BB*PP)    // 66560

// ws layout (byte offsets)
#define WS_SN     0         // sents_norm fp32: 128*512*4 = 262144
#define WS_SNB    262144    // sents_norm bf16: 128*512*2 = 131072
#define WS_IDX    393216    // idx: 2080 i32 = 8320
#define WS_IV     401536    // iv_all: 256*128*4 = 131072
#define WS_NEGQ   532608    // neg_sum_q: 128*4 = 512

typedef short bf16x8 __attribute__((ext_vector_type(8)));   // 8 bf16 raw (4 VGPRs)
typedef float f32x4  __attribute__((ext_vector_type(4)));   // MFMA accumulator

__device__ __forceinline__ unsigned short f2bf(float x) {
    unsigned int u = __float_as_uint(x);
    unsigned int r = (u + 0x7fffu + ((u >> 16) & 1u)) >> 16;   // RNE
    return (unsigned short)r;
}

// ---------------------------------------------------------------------------
// prep: blocks 0..127 normalize sents rows (fp32 + bf16 copies);
//       128..143 build idx table; 144 zeroes negq.
__global__ void k_prep(const float* __restrict__ sents, float* __restrict__ sn,
                       unsigned short* __restrict__ snb,
                       int* __restrict__ idx, float* __restrict__ negq) {
    const int blk = blockIdx.x, t = threadIdx.x;
    if (blk < 128) {
        __shared__ float red[256];
        const float* row = sents + (size_t)blk * CC;
        float x0 = row[t], x1 = row[t + 256];
        red[t] = x0 * x0 + x1 * x1;
        __syncthreads();
        for (int off = 128; off > 0; off >>= 1) {
            if (t < off) red[t] += red[t + off];
            __syncthreads();
        }
        float rn = 1.0f / fmaxf(sqrtf(red[0]), 1e-12f);
        float y0 = x0 * rn, y1 = x1 * rn;
        sn[(size_t)blk * CC + t]        = y0;
        sn[(size_t)blk * CC + t + 256]  = y1;
        snb[(size_t)blk * CC + t]       = f2bf(y0);
        snb[(size_t)blk * CC + t + 256] = f2bf(y1);
    } else if (blk < 144) {
        int i = (blk - 128) * 256 + t;      // 0..4095
        int r = i >> 6, c = i & 63;
        if (c >= r) {
            int p = r * 64 - (r * (r - 1)) / 2 + (c - r);
            idx[p] = i;
        }
    } else {
        if (t < 128) negq[t] = 0.0f;
    }
}

// ---------------------------------------------------------------------------
// fused per-target kernel: argmax over P, gather+normalize top column,
// then iv[m][s] = dot(topcol_norm, sn[s]) for all 128 sentences.
__global__ void k_fused(const float* __restrict__ video, const float* __restrict__ sn,
                        const float* __restrict__ iou2ds, const int* __restrict__ idx,
                        float* __restrict__ iv) {
    const int m = blockIdx.x, t = threadIdx.x;   // 256 threads
    __shared__ float sv[256];
    __shared__ int   si[256];
    __shared__ float tvs[512];
    __shared__ float red[256];

    // --- argmax of iou2ds[m] over valid proposals (tie -> lowest p)
    {
        float best = -1e30f; int bi = 1 << 30;
        const float* row = iou2ds + (size_t)m * NSQ;
        for (int p = t; p < PP; p += 256) {
            float v = row[idx[p]];
            if (v > best || (v == best && p < bi)) { best = v; bi = p; }
        }
        sv[t] = best; si[t] = bi;
        __syncthreads();
        for (int off = 128; off > 0; off >>= 1) {
            if (t < off) {
                float v2 = sv[t + off]; int i2 = si[t + off];
                if (v2 > sv[t] || (v2 == sv[t] && i2 < si[t])) { sv[t] = v2; si[t] = i2; }
            }
            __syncthreads();
        }
    }
    const int flat = idx[si[0]];
    const int b = m >> 3;                     // scatter_m2v

    // --- gather + normalize the column
    const float* base = video + (size_t)b * CC * NSQ + flat;
    float x0 = base[(size_t)t * NSQ];
    float x1 = base[(size_t)(t + 256) * NSQ];
    red[t] = x0 * x0 + x1 * x1;
    __syncthreads();
    for (int off = 128; off > 0; off >>= 1) {
        if (t < off) red[t] += red[t + off];
        __syncthreads();
    }
    float rn = 1.0f / fmaxf(sqrtf(red[0]), 1e-12f);
    tvs[t] = x0 * rn;
    tvs[t + 256] = x1 * rn;
    __syncthreads();

    // --- iv row: thread (s = t&127, h = t>>7) computes half-dot
    const int s = t & 127, h = t >> 7;
    const float4* a4 = (const float4*)(tvs + h * 256);
    const float4* b4 = (const float4*)(sn + (size_t)s * CC + h * 256);
    float acc = 0.f;
#pragma unroll 8
    for (int c = 0; c < 64; c++) {
        float4 a = a4[c], bb = b4[c];
        acc += a.x * bb.x + a.y * bb.y + a.z * bb.z + a.w * bb.w;
    }
    __syncthreads();          // red reuse
    red[t] = acc;
    __syncthreads();
    if (t < 128) iv[(size_t)m * SS + t] = red[t] + red[t + 128];
}

// ---------------------------------------------------------------------------
// Big fused MFMA kernel: 128(S) x 128(cols) tile of the score matrix.
// bf16 MFMA GEMM vs raw video columns with fused fp32 sum-of-squares;
// epilogue: rnorm scale, masked exp, per-row reduce, atomicAdd negq[s].
#define BK 64
#define LDK 72   // padded k-stride (bf16 elements) -> 144 B rows, 2-way conflicts only

__global__ __launch_bounds__(256)
void k_big(const float* __restrict__ video, const unsigned short* __restrict__ snb,
           const float* __restrict__ iou2d, const int* __restrict__ idx,
           float* __restrict__ negq) {
    __shared__ unsigned short sA[128 * LDK];   // sents  [row][k]
    __shared__ unsigned short vB[128 * LDK];   // video  [col][k]
    __shared__ int   colb[128], colflat[128];
    __shared__ float colrn[128];
    __shared__ float sqpart[256];
    __shared__ float red[128][17];

    const int t    = threadIdx.x;
    const int w    = t >> 6;          // wave 0..3
    const int lane = t & 63;
    const int q    = lane >> 4;       // quad 0..3
    const int l15  = lane & 15;
    const int j0   = blockIdx.x * 128;

    // per-column metadata for epilogue
    if (t < 128) {
        int col = j0 + t;
        int b = col / PP;
        colb[t] = b;
        colflat[t] = idx[col - b * PP];
    }

    // loader identity: column jj, k-half kh (32 channels each)
    const int jj = t & 127;
    const int kh = t >> 7;
    int colL = j0 + jj;
    int bL = colL / PP;
    int flatL = idx[colL - bL * PP];
    const float* vbase = video + (size_t)bL * (CC * NSQ) + flatL;

    f32x4 acc[2][8];
#pragma unroll
    for (int i = 0; i < 2; i++)
#pragma unroll
        for (int j = 0; j < 8; j++) acc[i][j] = (f32x4){0.f, 0.f, 0.f, 0.f};

    float sqa = 0.f;

    for (int k0 = 0; k0 < CC; k0 += BK) {
        __syncthreads();
        // stage A: 128 rows x 64 k of bf16 sents (already bf16 in global)
#pragma unroll
        for (int it = 0; it < 4; it++) {
            int lin = t + it * 256;
            int row = lin >> 3, kc = (lin & 7) * 8;
            bf16x8 v = *(const bf16x8*)(snb + (size_t)row * CC + k0 + kc);
            *(bf16x8*)(sA + row * LDK + kc) = v;
        }
        // stage B: 128 cols x 64 k, fp32 gather -> bf16, fused sumsq
        {
            const float* vp = vbase + (size_t)(k0 + kh * 32) * NSQ;
#pragma unroll
            for (int g = 0; g < 4; g++) {
                unsigned short buf[8];
#pragma unroll
                for (int i = 0; i < 8; i++) {
                    float x = vp[(size_t)(g * 8 + i) * NSQ];
                    sqa += x * x;
                    buf[i] = f2bf(x);
                }
                *(bf16x8*)(vB + jj * LDK + kh * 32 + g * 8) = *(bf16x8*)buf;
            }
        }
        __syncthreads();
        // compute: two K=32 sub-steps
#pragma unroll
        for (int ks = 0; ks < BK; ks += 32) {
            bf16x8 a[2], bfr[8];
#pragma unroll
            for (int rt = 0; rt < 2; rt++) {
                int row = w * 32 + rt * 16 + l15;
                a[rt] = *(const bf16x8*)(sA + row * LDK + ks + q * 8);
            }
#pragma unroll
            for (int ct = 0; ct < 8; ct++) {
                int col = ct * 16 + l15;
                bfr[ct] = *(const bf16x8*)(vB + col * LDK + ks + q * 8);
            }
#pragma unroll
            for (int rt = 0; rt < 2; rt++)
#pragma unroll
                for (int ct = 0; ct < 8; ct++)
                    acc[rt][ct] = __builtin_amdgcn_mfma_f32_16x16x32_bf16(
                        a[rt], bfr[ct], acc[rt][ct], 0, 0, 0);
        }
    }

    // column reciprocal norms (fp32)
    sqpart[t] = sqa;
    __syncthreads();
    if (t < 128) colrn[t] = 1.0f / fmaxf(sqrtf(sqpart[t] + sqpart[t + 128]), 1e-12f);
    __syncthreads();

    // epilogue: scale, exp, mask, per-row partials
    // D layout: row = rt*16 + q*4 + reg (+ w*32), col = ct*16 + l15
#pragma unroll
    for (int rt = 0; rt < 2; rt++) {
#pragma unroll
        for (int r = 0; r < 4; r++) {
            int s = w * 32 + rt * 16 + q * 4 + r;
            float rowsum = 0.f;
#pragma unroll
            for (int ct = 0; ct < 8; ct++) {
                int c = ct * 16 + l15;
                float sc = acc[rt][ct][r] * colrn[c];
                float e = expf(sc * 10.0f);            // / T_TEMP
                if ((s >> 2) == colb[c]) {             // same-video block
                    if (iou2d[(size_t)s * NSQ + colflat[c]] > 0.5f) e = 0.f;
                }
                rowsum += e;
            }
            red[s][l15] = rowsum;   // unique (s, l15) per lane -- no race
        }
    }
    __syncthreads();
    if (t < 128) {
        float tot = 0.f;
#pragma unroll
        for (int x = 0; x < 16; x++) tot += red[t][x];
        atomicAdd(&negq[t], tot);
    }
}

// ---------------------------------------------------------------------------
// final losses
__global__ void k_final(const float* __restrict__ iv, const float* __restrict__ negq,
                        float* __restrict__ out) {
    const int t = threadIdx.x;   // 256 = M
    __shared__ float rv[256], rq[256];
    const float* row = iv + (size_t)t * SS;
    const int ms = t >> 1;       // scatter_m2s
    float pos = row[ms];
    float nv = 0.f;
    for (int s = 0; s < SS; s++) {
        float e = expf(row[s] * 10.0f);
        if (s == ms) e = 0.f;
        nv += e;
    }
    float pe = expf(pos * 10.0f);
    float lv = logf(pe + nv) - pos * 10.0f;
    float lq = logf(pe + negq[ms]) - pos * 10.0f;
    rv[t] = lv; rq[t] = lq;
    __syncthreads();
    for (int off = 128; off > 0; off >>= 1) {
        if (t < off) { rv[t] += rv[t + off]; rq[t] += rq[t + off]; }
        __syncthreads();
    }
    if (t == 0) {
        float liv = rv[0] / 256.f, liq = rq[0] / 256.f;
        out[0] = liv + liq;   // total (WEIGHT=1)
        out[1] = liv;
        out[2] = liq;
    }
}

// ---------------------------------------------------------------------------
extern "C" void kernel_launch(void* const* d_in, const int* in_sizes, int n_in,
                              void* d_out, int out_size, void* d_ws, size_t ws_size,
                              hipStream_t stream) {
    const float* video  = (const float*)d_in[0];   // (B,C,N,N)
    const float* sents  = (const float*)d_in[1];   // (S,C)
    const float* iou2d  = (const float*)d_in[4];   // (S,N,N)
    const float* iou2ds = (const float*)d_in[5];   // (M,N,N)
    float* out = (float*)d_out;

    char* ws = (char*)d_ws;
    float*          sn   = (float*)(ws + WS_SN);
    unsigned short* snb  = (unsigned short*)(ws + WS_SNB);
    int*            idx  = (int*)(ws + WS_IDX);
    float*          iv   = (float*)(ws + WS_IV);
    float*          negq = (float*)(ws + WS_NEGQ);

    k_prep <<<145, 256, 0, stream>>>(sents, sn, snb, idx, negq);
    k_big  <<<JJ / 128, 256, 0, stream>>>(video, snb, iou2d, idx, negq);
    k_fused<<<MM,  256, 0, stream>>>(video, sn, iou2ds, idx, iv);
    k_final<<<1,   256, 0, stream>>>(iv, negq, out);
}